// Round 4
// baseline (230.540 us; speedup 1.0000x reference)
//
#include <hip/hip_runtime.h>
#include <hip/hip_fp16.h>

// GRU encoder: B=64, T=24, N=184, HID=128, in_dim 2 (prev fc out, pm_t).
// R4: exact co-residency. BN = 11776 = 512 * 23 -> 512 blocks x 512 threads,
// 23 rows/block (2 MFMA row-tiles of 16, 9 pad slots), __launch_bounds__(512,4)
// -> 2 blocks/CU, ENTIRE grid resident, no scheduling rounds/tail.
// Each wave owns 16 hidden cols (8 waves x 16 = 128). fc folded into the
// recurrence (rank-1 fold into r,z B-frags; x via a 4th MFMA chain with fcw
// replicated). t=0 peeled (h0=0 -> no MFMA, no hf init needed). -log2e /
// 2*log2e folded into B-frags+biases so gates use raw v_exp_f32 (exp2).
// hf double-buffered -> exactly 1 barrier/step.

#define B_   64
#define T_   24
#define N_   184
#define H_   128
#define BN   (B_ * N_)            // 11776
#define TN   (T_ * N_)            // 4416
#define HSZ  (B_ * T_ * N_ * H_)  // 36175872
#define MROWS 23
#define RSLOT 32                  // 2 row-tiles of 16 (rows 23..31 are pad)
#define NBLK  (BN / MROWS)        // 512, exact
#define S16   136                 // f16 h row stride in halves (272B, 16B-aligned)

typedef _Float16 v8h __attribute__((ext_vector_type(8)));
typedef float    v4f __attribute__((ext_vector_type(4)));

static __device__ __forceinline__ float fast_rcp(float x) {
#if __has_builtin(__builtin_amdgcn_rcpf)
    return __builtin_amdgcn_rcpf(x);
#else
    return 1.0f / x;
#endif
}
static __device__ __forceinline__ float fast_exp2(float x) {
#if __has_builtin(__builtin_amdgcn_exp2f)
    return __builtin_amdgcn_exp2f(x);
#else
    return __exp2f(x);
#endif
}
// sigmoid(s) with s pre-scaled by -log2e: 1/(1+2^s)
static __device__ __forceinline__ float sigm2(float s) {
    return fast_rcp(1.0f + fast_exp2(s));
}
// tanh(y) with y pre-scaled by 2*log2e: 1 - 2/(2^y+1)
static __device__ __forceinline__ float tanh2(float y) {
    return 1.0f - 2.0f * fast_rcp(1.0f + fast_exp2(y));
}

__global__ __launch_bounds__(512, 4)
void gru_encoder_kernel(const float* __restrict__ pm,    // [B,T,N]
                        const float* __restrict__ Wih,   // [384,2]
                        const float* __restrict__ Whh,   // [384,128]
                        const float* __restrict__ bih,   // [384]
                        const float* __restrict__ bhh,   // [384]
                        const float* __restrict__ fcw,   // [128]
                        const float* __restrict__ fcb,   // [1]
                        float* __restrict__ out)         // [HSZ] H + [BN] xn
{
    __shared__ _Float16 hf[2][RSLOT * S16];   // double-buffered f16 h (A operand)
    __shared__ float    pml[T_ * MROWS + 16]; // pm [t][row] + pad for lane over-read

    const int tid  = threadIdx.x;
    const int w    = tid >> 6;   // wave 0..7
    const int lane = tid & 63;
    const int u    = lane & 15;  // A-row / C-col selector
    const int q    = lane >> 4;  // quad
    const int i    = w * 16 + u; // this lane's hidden column (0..127)

    // ---- preload pm for this block's 23 rows, all 24 steps ----
    for (int idx = tid; idx < T_ * MROWS; idx += 512) {
        const int t   = idx / MROWS;
        const int row = idx - t * MROWS;
        const int g   = blockIdx.x * MROWS + row;   // < BN always (511*23+22 = 11775)
        const int b   = g / N_;
        pml[idx] = pm[b * TN + t * N_ + (g - b * N_)];
    }
    if (tid < 16) pml[T_ * MROWS + tid] = 0.0f;  // pad rows read past the end

    const float LOG2E = 1.4426950408889634f;
    const float C2    = 2.0f * LOG2E;

    // ---- B-fragments (once). r,z: -log2e*(Whh + Wih[:,0] (x) fcw); n: 2log2e*Whh ----
    // lane holds B[ks*32 + q*8 + j][i]
    v8h bfr[3][4];
#pragma unroll
    for (int g = 0; g < 3; ++g) {
        const int c = g * 128 + i;
        const float fold  = (g < 2) ? Wih[c * 2 + 0] : 0.0f;
        const float scale = (g < 2) ? -LOG2E : C2;
#pragma unroll
        for (int ks = 0; ks < 4; ++ks) {
            v8h hb;
#pragma unroll
            for (int j = 0; j < 8; ++j) {
                const int k = ks * 32 + q * 8 + j;
                hb[j] = (_Float16)(scale * (Whh[c * 128 + k] + fold * fcw[k]));
            }
            bfr[g][ks] = hb;
        }
    }
    // x-projection B: fcw replicated in every column -> accx[reg] = fcw . h[row]
    v8h bfx[4];
#pragma unroll
    for (int ks = 0; ks < 4; ++ks) {
        v8h hb;
#pragma unroll
        for (int j = 0; j < 8; ++j) hb[j] = (_Float16)fcw[ks * 32 + q * 8 + j];
        bfx[ks] = hb;
    }

    // ---- per-lane constants (pre-scaled) ----
    const float fcbv = fcb[0];
    const float w1r  = -LOG2E * Wih[(0 * 128 + i) * 2 + 1];
    const float w1z  = -LOG2E * Wih[(1 * 128 + i) * 2 + 1];
    const float w1n  = C2 * Wih[(2 * 128 + i) * 2 + 1];
    const float w0n  = C2 * Wih[(2 * 128 + i) * 2 + 0];
    const float brz_r0 = -LOG2E * (bih[0 * 128 + i] + bhh[0 * 128 + i]);
    const float brz_z0 = -LOG2E * (bih[1 * 128 + i] + bhh[1 * 128 + i]);
    const float brz_r1 = brz_r0 - LOG2E * Wih[(0 * 128 + i) * 2 + 0] * fcbv;
    const float brz_z1 = brz_z0 - LOG2E * Wih[(1 * 128 + i) * 2 + 0] * fcbv;
    const float bin_ = C2 * bih[2 * 128 + i];
    const float bhn_ = C2 * bhh[2 * 128 + i];

    // ---- per-lane row output bases; -1 marks pad rows (lr >= 23) ----
    int obase[2][4];
#pragma unroll
    for (int rt = 0; rt < 2; ++rt)
#pragma unroll
        for (int reg = 0; reg < 4; ++reg) {
            const int lr = rt * 16 + q * 4 + reg;
            if (lr < MROWS) {
                const int g = blockIdx.x * MROWS + lr;
                const int b = g / N_;
                obase[rt][reg] = b * TN + (g - b * N_);
            } else {
                obase[rt][reg] = -1;
            }
        }

    v4f hreg[2];
    hreg[0] = (v4f){0.f, 0.f, 0.f, 0.f};
    hreg[1] = (v4f){0.f, 0.f, 0.f, 0.f};

    __syncthreads();  // pml ready

    // ===== t = 0 peeled: h0 = 0 -> all MFMA accs are 0, x0 = 0 =====
#pragma unroll
    for (int rt = 0; rt < 2; ++rt) {
#pragma unroll
        for (int reg = 0; reg < 4; ++reg) {
            const int lr   = rt * 16 + q * 4 + reg;
            const float pmv = pml[lr];
            const float r  = sigm2(pmv * w1r + brz_r0);
            const float z  = sigm2(pmv * w1z + brz_z0);
            const float nt = tanh2(pmv * w1n + bin_ + r * bhn_);
            const float hnew = nt - z * nt;   // hreg == 0
            hreg[rt][reg] = hnew;
            hf[1][lr * S16 + i] = (_Float16)hnew;
            const int ob = obase[rt][reg];
            if (ob >= 0) out[(size_t)ob * H_ + i] = hnew;
        }
    }
    __syncthreads();

    // ===== t = 1 .. T-1 =====
    for (int t = 1; t < T_; ++t) {
        const _Float16* hfr = hf[t & 1];
        _Float16*       hfw = hf[(t + 1) & 1];
        const int tN = t * N_;
#pragma unroll
        for (int rt = 0; rt < 2; ++rt) {
            // --- MFMA: [ghr*, ghz*, ghn*, x] = h_{t-1} @ B ---
            v4f acc0 = (v4f){0.f, 0.f, 0.f, 0.f};
            v4f acc1 = (v4f){0.f, 0.f, 0.f, 0.f};
            v4f acc2 = (v4f){0.f, 0.f, 0.f, 0.f};
            v4f accx = (v4f){0.f, 0.f, 0.f, 0.f};
#pragma unroll
            for (int ks = 0; ks < 4; ++ks) {
                const v8h afr = *(const v8h*)&hfr[(rt * 16 + u) * S16 + ks * 32 + q * 8];
                acc0 = __builtin_amdgcn_mfma_f32_16x16x32_f16(afr, bfr[0][ks], acc0, 0, 0, 0);
                acc1 = __builtin_amdgcn_mfma_f32_16x16x32_f16(afr, bfr[1][ks], acc1, 0, 0, 0);
                acc2 = __builtin_amdgcn_mfma_f32_16x16x32_f16(afr, bfr[2][ks], acc2, 0, 0, 0);
                accx = __builtin_amdgcn_mfma_f32_16x16x32_f16(afr, bfx[ks],    accx, 0, 0, 0);
            }
            // --- gates + h update + stores ---
#pragma unroll
            for (int reg = 0; reg < 4; ++reg) {
                const int lr   = rt * 16 + q * 4 + reg;
                const float pmv = pml[t * MROWS + lr];
                const float xv  = accx[reg] + fcbv;           // x_t = fc(h_{t-1})
                const float r   = sigm2(acc0[reg] + pmv * w1r + brz_r1);
                const float z   = sigm2(acc1[reg] + pmv * w1z + brz_z1);
                const float nt  = tanh2(xv * w0n + pmv * w1n + bin_ +
                                        r * (acc2[reg] + bhn_));
                const float hnew = nt + z * (hreg[rt][reg] - nt);
                hreg[rt][reg] = hnew;
                hfw[lr * S16 + i] = (_Float16)hnew;
                const int ob = obase[rt][reg];
                if (ob >= 0) out[(size_t)(ob + tN) * H_ + i] = hnew;
            }
        }
        __syncthreads();  // hfw complete before next step's MFMA reads
    }

    // ===== epilogue: xn = fc(h_{T-1}); h_{T-1} is in hf[T_ & 1] = hf[0] =====
    if (w < 2) {
        const int rt = w;
        v4f accx = (v4f){0.f, 0.f, 0.f, 0.f};
#pragma unroll
        for (int ks = 0; ks < 4; ++ks) {
            const v8h afr = *(const v8h*)&hf[0][(rt * 16 + u) * S16 + ks * 32 + q * 8];
            accx = __builtin_amdgcn_mfma_f32_16x16x32_f16(afr, bfx[ks], accx, 0, 0, 0);
        }
        if (u == 0) {
#pragma unroll
            for (int reg = 0; reg < 4; ++reg) {
                const int lr = rt * 16 + q * 4 + reg;
                if (lr < MROWS)
                    out[(size_t)HSZ + blockIdx.x * MROWS + lr] = accx[reg] + fcbv;
            }
        }
    }
}

extern "C" void kernel_launch(void* const* d_in, const int* in_sizes, int n_in,
                              void* d_out, int out_size, void* d_ws, size_t ws_size,
                              hipStream_t stream) {
    const float* pm  = (const float*)d_in[0];  // [B,T,N,1]
    const float* Wih = (const float*)d_in[1];  // [384,2]
    const float* Whh = (const float*)d_in[2];  // [384,128]
    const float* bih = (const float*)d_in[3];  // [384]
    const float* bhh = (const float*)d_in[4];  // [384]
    const float* fcw = (const float*)d_in[5];  // [1,128]
    const float* fcb = (const float*)d_in[6];  // [1]
    float* out = (float*)d_out;

    gru_encoder_kernel<<<dim3(NBLK), dim3(512), 0, stream>>>(
        pm, Wih, Whh, bih, bhh, fcw, fcb, out);
}